// Round 2
// baseline (664.417 us; speedup 1.0000x reference)
//
#include <hip/hip_runtime.h>
#include <hip/hip_bf16.h>

#define SEQ   2048
#define BS    4
#define DM    1024
#define NH    16
#define ROWS  (BS*SEQ)   // 8192

using s16x8 = __attribute__((ext_vector_type(8))) short;
using f32x4 = __attribute__((ext_vector_type(4))) float;

#define MFMA16(a,b,c) __builtin_amdgcn_mfma_f32_16x16x32_bf16(a,b,c,0,0,0)

__device__ __forceinline__ short f2bf(float f){
  union { float f; unsigned u; } v; v.f = f;
  unsigned r = (v.u + 0x7FFFu + ((v.u >> 16) & 1u)) >> 16;
  return (short)r;
}

__device__ __forceinline__ float bf2f(short s){
  union { unsigned u; float f; } v; v.u = ((unsigned)(unsigned short)s) << 16;
  return v.f;
}

__device__ __forceinline__ void gload_lds16(const void* g, void* l){
  __builtin_amdgcn_global_load_lds(
    (const __attribute__((address_space(1))) unsigned int*)g,
    (__attribute__((address_space(3))) unsigned int*)l, 16, 0, 0);
}

// ---------------- mask pack: int32 -> bit per element -------------------
__global__ __launch_bounds__(256) void pack_mask(const int* __restrict__ mask,
                                                 unsigned* __restrict__ bits){
  int t = blockIdx.x * 256 + threadIdx.x;           // 16777216 threads
  unsigned long long b = __ballot(mask[t] != 0);
  int lane = threadIdx.x & 63;
  if (lane == 0)       bits[t >> 5] = (unsigned)b;
  else if (lane == 32) bits[t >> 5] = (unsigned)(b >> 32);
}

// ---------------- f32 -> bf16 convert ----------------------------------
__global__ __launch_bounds__(256) void conv_bf16(const float* __restrict__ in,
                                                 short* __restrict__ out){
  int t = blockIdx.x * 256 + threadIdx.x;
  float4 v = ((const float4*)in)[t];
  short4 o;
  o.x = f2bf(v.x); o.y = f2bf(v.y); o.z = f2bf(v.z); o.w = f2bf(v.w);
  ((short4*)out)[t] = o;
}

// ---------------- weight transpose+convert: W[k][n] -> Wt[n][k] bf16 ---
__global__ __launch_bounds__(256) void transpose_w(const float* __restrict__ W,
                                                   short* __restrict__ Wt){
  __shared__ float tile[32][33];
  int n0 = blockIdx.x * 32, k0 = blockIdx.y * 32;
  int tx = threadIdx.x, ty = threadIdx.y;   // (32,8)
  #pragma unroll
  for (int i = 0; i < 32; i += 8)
    tile[ty + i][tx] = W[(size_t)(k0 + ty + i) * DM + n0 + tx];
  __syncthreads();
  #pragma unroll
  for (int i = 0; i < 32; i += 8)
    Wt[(size_t)(n0 + ty + i) * DM + k0 + tx] = f2bf(tile[tx][ty + i]);
}

// ---------------- 128x128 bf16 GEMM (B^T input) + bias, f32 out --------
// C[M][1024] = A[M][1024] * Bt[1024][1024]^T + bias
__global__ __launch_bounds__(256) void gemm_bias(const short* __restrict__ A,
                                                 const short* __restrict__ Bt,
                                                 const float* __restrict__ bias,
                                                 float* __restrict__ C){
  __shared__ short As[128 * 32];
  __shared__ short Bs[128 * 32];
  const int tid = threadIdx.x;
  const int wid = tid >> 6, lane = tid & 63;
  const int m0 = blockIdx.y * 128, n0 = blockIdx.x * 128;
  const int wr = (wid >> 1) * 64, wc = (wid & 1) * 64;
  const int lrow = lane & 15, lk = lane >> 4;
  f32x4 acc[4][4] = {};

  const int e0 = wid * 1024 + lane * 16;
  const int r0 = e0 >> 6, c0 = e0 & 63;
  const int e1 = e0 + 4096;
  const int r1 = e1 >> 6, c1 = e1 & 63;

  const char* Abase = (const char*)A + (size_t)m0 * 2048;
  const char* Bbase = (const char*)Bt + (size_t)n0 * 2048;
  char* AsB = (char*)As;
  char* BsB = (char*)Bs;

  for (int k0 = 0; k0 < DM; k0 += 32) {
    gload_lds16(Abase + (size_t)r0 * 2048 + k0 * 2 + c0, AsB + wid * 1024);
    gload_lds16(Abase + (size_t)r1 * 2048 + k0 * 2 + c1, AsB + 4096 + wid * 1024);
    gload_lds16(Bbase + (size_t)r0 * 2048 + k0 * 2 + c0, BsB + wid * 1024);
    gload_lds16(Bbase + (size_t)r1 * 2048 + k0 * 2 + c1, BsB + 4096 + wid * 1024);
    __syncthreads();
    s16x8 af[4], bf[4];
    #pragma unroll
    for (int mt = 0; mt < 4; mt++)
      af[mt] = *(const s16x8*)(AsB + ((wr + mt * 16 + lrow) * 64 + lk * 16));
    #pragma unroll
    for (int nt = 0; nt < 4; nt++)
      bf[nt] = *(const s16x8*)(BsB + ((wc + nt * 16 + lrow) * 64 + lk * 16));
    #pragma unroll
    for (int mt = 0; mt < 4; mt++)
      #pragma unroll
      for (int nt = 0; nt < 4; nt++)
        acc[mt][nt] = MFMA16(af[mt], bf[nt], acc[mt][nt]);
    __syncthreads();
  }
  #pragma unroll
  for (int nt = 0; nt < 4; nt++) {
    int col = n0 + wc + nt * 16 + lrow;
    float bv = bias[col];
    #pragma unroll
    for (int mt = 0; mt < 4; mt++) {
      #pragma unroll
      for (int r = 0; r < 4; r++) {
        int row = m0 + wr + mt * 16 + lk * 4 + r;
        C[(size_t)row * DM + col] = acc[mt][nt][r] + bv;
      }
    }
  }
}

// ---------------- LayerNorm + scale/bias + head-split, bf16 out --------
// in: Y[8192][1024] f32 ; out: [b][h][s][64] bf16
__global__ __launch_bounds__(256) void ln_to_heads(const float* __restrict__ Y,
                                                   const float* __restrict__ sc,
                                                   const float* __restrict__ bi,
                                                   short* __restrict__ out){
  int row = blockIdx.x;                 // b*2048 + s
  int b = row >> 11, s = row & 2047;
  int tid = threadIdx.x;
  float4 v = ((const float4*)(Y + (size_t)row * DM))[tid];
  float sum = v.x + v.y + v.z + v.w;
  float sq  = v.x * v.x + v.y * v.y + v.z * v.z + v.w * v.w;
  #pragma unroll
  for (int o = 32; o; o >>= 1) { sum += __shfl_down(sum, o); sq += __shfl_down(sq, o); }
  __shared__ float red[8];
  int wid = tid >> 6, lane = tid & 63;
  if (!lane) { red[wid] = sum; red[wid + 4] = sq; }
  __syncthreads();
  sum = red[0] + red[1] + red[2] + red[3];
  sq  = red[4] + red[5] + red[6] + red[7];
  float mu = sum * (1.0f / DM);
  float var = sq * (1.0f / DM) - mu * mu;
  float rs = rsqrtf(var + 1e-6f);
  float4 scv = ((const float4*)sc)[tid];
  float4 biv = ((const float4*)bi)[tid];
  short4 o4;
  o4.x = f2bf((v.x - mu) * rs * scv.x + biv.x);
  o4.y = f2bf((v.y - mu) * rs * scv.y + biv.y);
  o4.z = f2bf((v.z - mu) * rs * scv.z + biv.z);
  o4.w = f2bf((v.w - mu) * rs * scv.w + biv.w);
  int c = tid * 4;
  int h = c >> 6, d = c & 63;
  *(short4*)(out + (((size_t)(b * NH + h) * SEQ + s) * 64 + d)) = o4;
}

// ---------------- flash attention ---------------------------------------
// Qh/Kh/Vh: [b][h][s][64] bf16 ; mbits: [b][q][64 words] ; AO: [b][s][h*64+d] bf16
__global__ __launch_bounds__(256) void attn(const short* __restrict__ Qh,
                                            const short* __restrict__ Kh,
                                            const short* __restrict__ Vh,
                                            const unsigned* __restrict__ mbits,
                                            short* __restrict__ AO){
  __shared__ short Ks[64 * 64];
  __shared__ short Vt[64 * 64];
  __shared__ short Pl[4][16 * 64];
  const int tid = threadIdx.x, wid = tid >> 6, lane = tid & 63;
  const int bh = blockIdx.y, b = bh >> 4, h = bh & 15;
  const int q0 = blockIdx.x * 64;
  const size_t bhoff = (size_t)bh * SEQ * 64;
  const int lrow = lane & 15, lg = lane >> 4;
  const float L2E = 1.44269504f;

  s16x8 qf[2];
  {
    const short* qrow = Qh + bhoff + (size_t)(q0 + wid * 16 + lrow) * 64 + lg * 8;
    qf[0] = *(const s16x8*)(qrow);
    qf[1] = *(const s16x8*)(qrow + 32);
  }
  f32x4 o[4] = {};
  float m_[4], l_[4];
  #pragma unroll
  for (int r = 0; r < 4; r++) { m_[r] = -1e9f; l_[r] = 0.f; }

  const unsigned* mrow[4];
  #pragma unroll
  for (int r = 0; r < 4; r++)
    mrow[r] = mbits + ((size_t)b * SEQ + (q0 + wid * 16 + lg * 4 + r)) * 64;

  // K staging geometry (pre-swizzled global source, linear LDS dest)
  const int eK0 = wid * 1024 + lane * 16;
  const int kr0 = eK0 >> 7, kc0s = (eK0 & 127) ^ ((kr0 & 7) << 4);
  const int eK1 = eK0 + 4096;
  const int kr1 = eK1 >> 7, kc1s = (eK1 & 127) ^ ((kr1 & 7) << 4);
  const char* Kbase = (const char*)(Kh + bhoff);
  char* KsB = (char*)Ks;
  char* VtB = (char*)Vt;
  char* PlB = (char*)&Pl[wid][0];
  const int vkr = tid >> 2, vdb = (tid & 3) * 16;
  const short* Vbase = Vh + bhoff;

  for (int k0 = 0; k0 < SEQ; k0 += 64) {
    gload_lds16(Kbase + (size_t)(k0 + kr0) * 128 + kc0s, KsB + wid * 1024);
    gload_lds16(Kbase + (size_t)(k0 + kr1) * 128 + kc1s, KsB + 4096 + wid * 1024);
    {
      const short* vsrc = Vbase + (size_t)(k0 + vkr) * 64 + vdb;
      s16x8 v0 = *(const s16x8*)(vsrc);
      s16x8 v1 = *(const s16x8*)(vsrc + 8);
      #pragma unroll
      for (int j = 0; j < 8; j++) {
        int d = vdb + j;
        *(short*)(VtB + d * 128 + ((vkr * 2) ^ ((d & 7) << 4))) = v0[j];
      }
      #pragma unroll
      for (int j = 0; j < 8; j++) {
        int d = vdb + 8 + j;
        *(short*)(VtB + d * 128 + ((vkr * 2) ^ ((d & 7) << 4))) = v1[j];
      }
    }
    __syncthreads();

    // mask words for this 64-key tile
    unsigned mw[4][2];
    #pragma unroll
    for (int r = 0; r < 4; r++) {
      mw[r][0] = mrow[r][(k0 >> 5)];
      mw[r][1] = mrow[r][(k0 >> 5) + 1];
    }

    float p[4][4];
    float tmax[4] = {-3e38f, -3e38f, -3e38f, -3e38f};
    #pragma unroll
    for (int kt = 0; kt < 4; kt++) {
      f32x4 sacc = {};
      #pragma unroll
      for (int c = 0; c < 2; c++) {
        int krow = kt * 16 + lrow;
        s16x8 kf = *(const s16x8*)(KsB + krow * 128 + ((lg * 16 + 64 * c) ^ ((krow & 7) << 4)));
        sacc = MFMA16(qf[c], kf, sacc);
      }
      int bit = ((kt & 1) * 16 + lrow);
      #pragma unroll
      for (int r = 0; r < 4; r++) {
        bool on = (mw[r][kt >> 1] >> bit) & 1;
        float sv = on ? sacc[r] * 0.125f : -1e9f;
        p[kt][r] = sv;
        tmax[r] = fmaxf(tmax[r], sv);
      }
    }
    #pragma unroll
    for (int r = 0; r < 4; r++) {
      float t = tmax[r];
      t = fmaxf(t, __shfl_xor(t, 1));
      t = fmaxf(t, __shfl_xor(t, 2));
      t = fmaxf(t, __shfl_xor(t, 4));
      t = fmaxf(t, __shfl_xor(t, 8));
      float mn = fmaxf(m_[r], t);
      float sc = exp2f((m_[r] - mn) * L2E);
      m_[r] = mn;
      l_[r] *= sc;
      o[0][r] *= sc; o[1][r] *= sc; o[2][r] *= sc; o[3][r] *= sc;
    }
    float rsum[4] = {0, 0, 0, 0};
    #pragma unroll
    for (int kt = 0; kt < 4; kt++) {
      #pragma unroll
      for (int r = 0; r < 4; r++) {
        float e = exp2f((p[kt][r] - m_[r]) * L2E);
        short eb = f2bf(e);
        rsum[r] += bf2f(eb);            // denominator matches bf16 P used in PV
        int prow = lg * 4 + r;
        int colb = (kt * 16 + lrow) * 2;
        *(short*)(PlB + prow * 128 + (colb ^ ((prow & 7) << 4))) = eb;
      }
    }
    #pragma unroll
    for (int r = 0; r < 4; r++) {
      float t = rsum[r];
      t += __shfl_xor(t, 1); t += __shfl_xor(t, 2);
      t += __shfl_xor(t, 4); t += __shfl_xor(t, 8);
      l_[r] += t;
    }
    #pragma unroll
    for (int dt = 0; dt < 4; dt++) {
      #pragma unroll
      for (int kc = 0; kc < 2; kc++) {
        s16x8 pf = *(const s16x8*)(PlB + lrow * 128 + ((lg * 16 + kc * 64) ^ ((lrow & 7) << 4)));
        int vrow = dt * 16 + lrow;
        s16x8 vf = *(const s16x8*)(VtB + vrow * 128 + ((lg * 16 + kc * 64) ^ ((vrow & 7) << 4)));
        o[dt] = MFMA16(pf, vf, o[dt]);
      }
    }
    __syncthreads();
  }
  #pragma unroll
  for (int r = 0; r < 4; r++) {
    float inv = 1.0f / l_[r];
    int qrow = q0 + wid * 16 + lg * 4 + r;
    size_t orow = ((size_t)b * SEQ + qrow) * DM + h * 64;
    #pragma unroll
    for (int dt = 0; dt < 4; dt++)
      AO[orow + dt * 16 + lrow] = f2bf(o[dt][r] * inv);
  }
}

// ------------------------------------------------------------------------
extern "C" void kernel_launch(void* const* d_in, const int* in_sizes, int n_in,
                              void* d_out, int out_size, void* d_ws, size_t ws_size,
                              hipStream_t stream) {
  const float* kv  = (const float*)d_in[0];
  const float* q   = (const float*)d_in[1];
  const int*   msk = (const int*)d_in[2];
  const float* Wq  = (const float*)d_in[3];
  const float* bq  = (const float*)d_in[4];
  const float* Wk  = (const float*)d_in[5];
  const float* bk  = (const float*)d_in[6];
  const float* Wv  = (const float*)d_in[7];
  const float* bv  = (const float*)d_in[8];
  const float* qns = (const float*)d_in[9];
  const float* qnb = (const float*)d_in[10];
  const float* kns = (const float*)d_in[11];
  const float* knb = (const float*)d_in[12];
  const float* vns = (const float*)d_in[13];
  const float* vnb = (const float*)d_in[14];
  const float* Wo  = (const float*)d_in[15];
  const float* bo  = (const float*)d_in[16];
  float* out = (float*)d_out;
  char* ws = (char*)d_ws;
  const size_t MB = 1u << 20;

  short* wqt   = (short*)(ws + 0 * MB);
  short* wkt   = (short*)(ws + 2 * MB);
  short* wvt   = (short*)(ws + 4 * MB);
  short* wot   = (short*)(ws + 6 * MB);
  short* qb    = (short*)(ws + 8 * MB);
  short* kvb   = (short*)(ws + 24 * MB);
  float* Y     = (float*)(ws + 40 * MB);
  short* Qh    = (short*)(ws + 72 * MB);
  short* Kh    = (short*)(ws + 88 * MB);
  short* Vh    = (short*)(ws + 104 * MB);
  short* AO    = (short*)(ws + 120 * MB);
  unsigned* mb = (unsigned*)(ws + 136 * MB);

  pack_mask<<<dim3(65536), dim3(256), 0, stream>>>(msk, mb);
  conv_bf16<<<dim3(ROWS * DM / 1024), dim3(256), 0, stream>>>(q, qb);
  conv_bf16<<<dim3(ROWS * DM / 1024), dim3(256), 0, stream>>>(kv, kvb);
  transpose_w<<<dim3(32, 32), dim3(32, 8), 0, stream>>>(Wq, wqt);
  transpose_w<<<dim3(32, 32), dim3(32, 8), 0, stream>>>(Wk, wkt);
  transpose_w<<<dim3(32, 32), dim3(32, 8), 0, stream>>>(Wv, wvt);
  transpose_w<<<dim3(32, 32), dim3(32, 8), 0, stream>>>(Wo, wot);

  gemm_bias<<<dim3(8, 64), dim3(256), 0, stream>>>(qb, wqt, bq, Y);
  ln_to_heads<<<dim3(ROWS), dim3(256), 0, stream>>>(Y, qns, qnb, Qh);
  gemm_bias<<<dim3(8, 64), dim3(256), 0, stream>>>(kvb, wkt, bk, Y);
  ln_to_heads<<<dim3(ROWS), dim3(256), 0, stream>>>(Y, kns, knb, Kh);
  gemm_bias<<<dim3(8, 64), dim3(256), 0, stream>>>(kvb, wvt, bv, Y);
  ln_to_heads<<<dim3(ROWS), dim3(256), 0, stream>>>(Y, vns, vnb, Vh);

  attn<<<dim3(SEQ / 64, BS * NH), dim3(256), 0, stream>>>(Qh, Kh, Vh, mb, AO);

  gemm_bias<<<dim3(8, 64), dim3(256), 0, stream>>>(AO, wot, bo, out);
}

// Round 3
// 567.761 us; speedup vs baseline: 1.1702x; 1.1702x over previous
//
#include <hip/hip_runtime.h>
#include <hip/hip_bf16.h>

#define SEQ   2048
#define BS    4
#define DM    1024
#define NH    16
#define ROWS  (BS*SEQ)   // 8192

using s16x8 = __attribute__((ext_vector_type(8))) short;
using f32x4 = __attribute__((ext_vector_type(4))) float;

#define MFMA16(a,b,c) __builtin_amdgcn_mfma_f32_16x16x32_bf16(a,b,c,0,0,0)

__device__ __forceinline__ short f2bf(float f){
  union { float f; unsigned u; } v; v.f = f;
  unsigned r = (v.u + 0x7FFFu + ((v.u >> 16) & 1u)) >> 16;
  return (short)r;
}

__device__ __forceinline__ float bf2f(short s){
  union { unsigned u; float f; } v; v.u = ((unsigned)(unsigned short)s) << 16;
  return v.f;
}

__device__ __forceinline__ float bpermf(float v, int srcLane){
  union { float f; int i; } u; u.f = v;
  u.i = __builtin_amdgcn_ds_bpermute(srcLane * 4, u.i);
  return u.f;
}

__device__ __forceinline__ void gload_lds16(const void* g, void* l){
  __builtin_amdgcn_global_load_lds(
    (const __attribute__((address_space(1))) unsigned int*)g,
    (__attribute__((address_space(3))) unsigned int*)l, 16, 0, 0);
}

// ---------------- mask pack: int32 -> bit per element -------------------
__global__ __launch_bounds__(256) void pack_mask(const int* __restrict__ mask,
                                                 unsigned* __restrict__ bits){
  int t = blockIdx.x * 256 + threadIdx.x;
  unsigned long long b = __ballot(mask[t] != 0);
  int lane = threadIdx.x & 63;
  if (lane == 0)       bits[t >> 5] = (unsigned)b;
  else if (lane == 32) bits[t >> 5] = (unsigned)(b >> 32);
}

// ---------------- f32 -> bf16 convert ----------------------------------
__global__ __launch_bounds__(256) void conv_bf16(const float* __restrict__ in,
                                                 short* __restrict__ out){
  int t = blockIdx.x * 256 + threadIdx.x;
  float4 v = ((const float4*)in)[t];
  short4 o;
  o.x = f2bf(v.x); o.y = f2bf(v.y); o.z = f2bf(v.z); o.w = f2bf(v.w);
  ((short4*)out)[t] = o;
}

// ---------------- weight transpose+convert: W[k][n] -> Wt[n][k] bf16 ---
__global__ __launch_bounds__(256) void transpose_w(const float* __restrict__ W,
                                                   short* __restrict__ Wt){
  __shared__ float tile[32][33];
  int n0 = blockIdx.x * 32, k0 = blockIdx.y * 32;
  int tx = threadIdx.x, ty = threadIdx.y;   // (32,8)
  #pragma unroll
  for (int i = 0; i < 32; i += 8)
    tile[ty + i][tx] = W[(size_t)(k0 + ty + i) * DM + n0 + tx];
  __syncthreads();
  #pragma unroll
  for (int i = 0; i < 32; i += 8)
    Wt[(size_t)(n0 + ty + i) * DM + k0 + tx] = f2bf(tile[tx][ty + i]);
}

// ---------------- 128x128 bf16 GEMM (B^T input) + bias, f32 out --------
__global__ __launch_bounds__(256) void gemm_bias(const short* __restrict__ A,
                                                 const short* __restrict__ Bt,
                                                 const float* __restrict__ bias,
                                                 float* __restrict__ C){
  __shared__ short As[128 * 32];
  __shared__ short Bs[128 * 32];
  const int tid = threadIdx.x;
  const int wid = tid >> 6, lane = tid & 63;
  const int m0 = blockIdx.y * 128, n0 = blockIdx.x * 128;
  const int wr = (wid >> 1) * 64, wc = (wid & 1) * 64;
  const int lrow = lane & 15, lk = lane >> 4;
  f32x4 acc[4][4] = {};

  const int e0 = wid * 1024 + lane * 16;
  const int r0 = e0 >> 6, c0 = e0 & 63;
  const int e1 = e0 + 4096;
  const int r1 = e1 >> 6, c1 = e1 & 63;

  const char* Abase = (const char*)A + (size_t)m0 * 2048;
  const char* Bbase = (const char*)Bt + (size_t)n0 * 2048;
  char* AsB = (char*)As;
  char* BsB = (char*)Bs;

  for (int k0 = 0; k0 < DM; k0 += 32) {
    gload_lds16(Abase + (size_t)r0 * 2048 + k0 * 2 + c0, AsB + wid * 1024);
    gload_lds16(Abase + (size_t)r1 * 2048 + k0 * 2 + c1, AsB + 4096 + wid * 1024);
    gload_lds16(Bbase + (size_t)r0 * 2048 + k0 * 2 + c0, BsB + wid * 1024);
    gload_lds16(Bbase + (size_t)r1 * 2048 + k0 * 2 + c1, BsB + 4096 + wid * 1024);
    __syncthreads();
    s16x8 af[4], bf[4];
    #pragma unroll
    for (int mt = 0; mt < 4; mt++)
      af[mt] = *(const s16x8*)(AsB + ((wr + mt * 16 + lrow) * 64 + lk * 16));
    #pragma unroll
    for (int nt = 0; nt < 4; nt++)
      bf[nt] = *(const s16x8*)(BsB + ((wc + nt * 16 + lrow) * 64 + lk * 16));
    #pragma unroll
    for (int mt = 0; mt < 4; mt++)
      #pragma unroll
      for (int nt = 0; nt < 4; nt++)
        acc[mt][nt] = MFMA16(af[mt], bf[nt], acc[mt][nt]);
    __syncthreads();
  }
  #pragma unroll
  for (int nt = 0; nt < 4; nt++) {
    int col = n0 + wc + nt * 16 + lrow;
    float bv = bias[col];
    #pragma unroll
    for (int mt = 0; mt < 4; mt++) {
      #pragma unroll
      for (int r = 0; r < 4; r++) {
        int row = m0 + wr + mt * 16 + lk * 4 + r;
        C[(size_t)row * DM + col] = acc[mt][nt][r] + bv;
      }
    }
  }
}

// ---------------- LayerNorm + scale/bias + head-split, bf16 out --------
__global__ __launch_bounds__(256) void ln_to_heads(const float* __restrict__ Y,
                                                   const float* __restrict__ sc,
                                                   const float* __restrict__ bi,
                                                   short* __restrict__ out){
  int row = blockIdx.x;                 // b*2048 + s
  int b = row >> 11, s = row & 2047;
  int tid = threadIdx.x;
  float4 v = ((const float4*)(Y + (size_t)row * DM))[tid];
  float sum = v.x + v.y + v.z + v.w;
  float sq  = v.x * v.x + v.y * v.y + v.z * v.z + v.w * v.w;
  #pragma unroll
  for (int o = 32; o; o >>= 1) { sum += __shfl_down(sum, o); sq += __shfl_down(sq, o); }
  __shared__ float red[8];
  int wid = tid >> 6, lane = tid & 63;
  if (!lane) { red[wid] = sum; red[wid + 4] = sq; }
  __syncthreads();
  sum = red[0] + red[1] + red[2] + red[3];
  sq  = red[4] + red[5] + red[6] + red[7];
  float mu = sum * (1.0f / DM);
  float var = sq * (1.0f / DM) - mu * mu;
  float rs = rsqrtf(var + 1e-6f);
  float4 scv = ((const float4*)sc)[tid];
  float4 biv = ((const float4*)bi)[tid];
  short4 o4;
  o4.x = f2bf((v.x - mu) * rs * scv.x + biv.x);
  o4.y = f2bf((v.y - mu) * rs * scv.y + biv.y);
  o4.z = f2bf((v.z - mu) * rs * scv.z + biv.z);
  o4.w = f2bf((v.w - mu) * rs * scv.w + biv.w);
  int c = tid * 4;
  int h = c >> 6, d = c & 63;
  *(short4*)(out + (((size_t)(b * NH + h) * SEQ + s) * 64 + d)) = o4;
}

// ---------------- V transpose: [bh][s][64] -> [bh][64][s] ---------------
__global__ __launch_bounds__(256) void transpose_v(const short* __restrict__ Vh,
                                                   short* __restrict__ Vt){
  __shared__ char t[8192];
  const int tid = threadIdx.x;
  const int bh = blockIdx.y;
  const int s0 = blockIdx.x * 64;
  const char* src = (const char*)(Vh + (size_t)bh * SEQ * 64 + (size_t)s0 * 64);
  char* dst = (char*)(Vt + (size_t)bh * 64 * SEQ + s0);
  #pragma unroll
  for (int p = 0; p < 2; p++) {
    int e = p * 4096 + tid * 16;
    int s = e >> 7, d2 = e & 127;
    s16x8 v = *(const s16x8*)(src + (size_t)s * 128 + d2);
    *(s16x8*)(t + s * 128 + (d2 ^ ((s & 7) << 4))) = v;
  }
  __syncthreads();
  #pragma unroll
  for (int p = 0; p < 2; p++) {
    int f = p * 4096 + tid * 16;
    int d = f >> 7;
    int sj = (f & 127) >> 1;
    s16x8 v;
    #pragma unroll
    for (int k = 0; k < 8; k++) {
      int s = sj + k;
      v[k] = *(const short*)(t + s * 128 + ((2 * d) ^ ((s & 7) << 4)));
    }
    *(s16x8*)(dst + (size_t)d * (SEQ * 2) + sj * 2) = v;
  }
}

// ---------------- flash attention (swapped QK^T) ------------------------
// Qh/Kh: [b][h][s][64] ; Vt: [b][h][64][s] ; mbits: [b][q][64w] ; AO: [b][s][DM]
__global__ __launch_bounds__(256) void attn(const short* __restrict__ Qh,
                                            const short* __restrict__ Kh,
                                            const short* __restrict__ VtG,
                                            const unsigned* __restrict__ mbits,
                                            short* __restrict__ AO){
  __shared__ short Ks[64 * 64];      // [k][d] rows swizzled ^((k&7)<<4)
  __shared__ short Vs[64 * 64];      // [d][s] rows swizzled ^((d&7)<<4)
  __shared__ short Pl[4][16 * 64];   // per-wave [q][k] rows swizzled ^((q&7)<<4)
  const int tid = threadIdx.x, wid = tid >> 6, lane = tid & 63;
  const int bh = blockIdx.y, b = bh >> 4, h = bh & 15;
  const int q0 = blockIdx.x * 64;
  const size_t bhoff = (size_t)bh * SEQ * 64;
  const int lrow = lane & 15, lg = lane >> 4;
  const float L2E = 1.44269504f;

  const int qidx = q0 + wid * 16 + lrow;      // this lane's softmax q-row
  s16x8 qf[2];
  {
    const short* qrow = Qh + bhoff + (size_t)qidx * 64 + lg * 8;
    qf[0] = *(const s16x8*)(qrow);
    qf[1] = *(const s16x8*)(qrow + 32);
  }
  f32x4 o[4] = {};
  float m_ = -1e9f, l_ = 0.f;

  const unsigned* mrow = mbits + ((size_t)b * SEQ + qidx) * 64;

  // staging geometry (pre-swizzled global source, linear LDS dest)
  const int e0 = wid * 1024 + lane * 16;
  const int sr0 = e0 >> 7, sc0 = (e0 & 127) ^ ((sr0 & 7) << 4);
  const int e1 = e0 + 4096;
  const int sr1 = e1 >> 7, sc1 = (e1 & 127) ^ ((sr1 & 7) << 4);
  const char* Kbase = (const char*)(Kh + bhoff);
  const char* Vbase = (const char*)(VtG + bhoff);   // rows d, stride SEQ*2
  char* KsB = (char*)Ks;
  char* VsB = (char*)Vs;
  char* PlB = (char*)&Pl[wid][0];

  for (int k0 = 0; k0 < SEQ; k0 += 64) {
    gload_lds16(Kbase + (size_t)(k0 + sr0) * 128 + sc0, KsB + wid * 1024);
    gload_lds16(Kbase + (size_t)(k0 + sr1) * 128 + sc1, KsB + 4096 + wid * 1024);
    gload_lds16(Vbase + (size_t)sr0 * (SEQ * 2) + k0 * 2 + sc0, VsB + wid * 1024);
    gload_lds16(Vbase + (size_t)sr1 * (SEQ * 2) + k0 * 2 + sc1, VsB + 4096 + wid * 1024);
    __syncthreads();

    const unsigned mw0 = mrow[(k0 >> 5)];
    const unsigned mw1 = mrow[(k0 >> 5) + 1];

    // swapped QK^T: S^T[k][q], lane owns q=qidx, k = kt*16 + lg*4 + r
    float sv[4][4];
    #pragma unroll
    for (int kt = 0; kt < 4; kt++) {
      f32x4 sacc = {};
      #pragma unroll
      for (int c = 0; c < 2; c++) {
        int krow = kt * 16 + lrow;
        s16x8 kf = *(const s16x8*)(KsB + krow * 128 + ((lg * 16 + 64 * c) ^ ((krow & 7) << 4)));
        sacc = MFMA16(kf, qf[c], sacc);
      }
      unsigned w = (kt < 2) ? mw0 : mw1;
      #pragma unroll
      for (int r = 0; r < 4; r++) {
        int bit = (kt & 1) * 16 + lg * 4 + r;
        bool on = (w >> bit) & 1;
        sv[kt][r] = on ? sacc[r] * 0.125f : -1e9f;
      }
    }
    // tile max (in-lane tree + 2 shfls)
    float t01 = fmaxf(fmaxf(sv[0][0], sv[0][1]), fmaxf(sv[0][2], sv[0][3]));
    float t11 = fmaxf(fmaxf(sv[1][0], sv[1][1]), fmaxf(sv[1][2], sv[1][3]));
    float t21 = fmaxf(fmaxf(sv[2][0], sv[2][1]), fmaxf(sv[2][2], sv[2][3]));
    float t31 = fmaxf(fmaxf(sv[3][0], sv[3][1]), fmaxf(sv[3][2], sv[3][3]));
    float tmax = fmaxf(fmaxf(t01, t11), fmaxf(t21, t31));
    tmax = fmaxf(tmax, __shfl_xor(tmax, 16));
    tmax = fmaxf(tmax, __shfl_xor(tmax, 32));

    // defer-max: rescale only when max grows materially (THR=8)
    if (__any(tmax > m_ + 8.0f)) {
      float mn = fmaxf(m_, tmax);
      float scl = exp2f((m_ - mn) * L2E);
      m_ = mn;
      l_ *= scl;
      #pragma unroll
      for (int r = 0; r < 4; r++) {
        float scr = bpermf(scl, lg * 4 + r);
        o[0][r] *= scr; o[1][r] *= scr; o[2][r] *= scr; o[3][r] *= scr;
      }
    }

    // exp, bf16-quantize, P write (4 x ds_write_b64), denom
    float rsum = 0.f;
    #pragma unroll
    for (int kt = 0; kt < 4; kt++) {
      float ee0 = exp2f((sv[kt][0] - m_) * L2E);
      float ee1 = exp2f((sv[kt][1] - m_) * L2E);
      float ee2 = exp2f((sv[kt][2] - m_) * L2E);
      float ee3 = exp2f((sv[kt][3] - m_) * L2E);
      short b0 = f2bf(ee0), b1 = f2bf(ee1), b2 = f2bf(ee2), b3 = f2bf(ee3);
      rsum += bf2f(b0) + bf2f(b1) + bf2f(b2) + bf2f(b3);
      uint2 wv;
      wv.x = (unsigned)(unsigned short)b0 | ((unsigned)(unsigned short)b1 << 16);
      wv.y = (unsigned)(unsigned short)b2 | ((unsigned)(unsigned short)b3 << 16);
      *(uint2*)(PlB + lrow * 128 + ((32 * kt + 8 * lg) ^ ((lrow & 7) << 4))) = wv;
    }
    rsum += __shfl_xor(rsum, 16);
    rsum += __shfl_xor(rsum, 32);
    l_ += rsum;

    // PV: O[q][d] += P[q][k] * Vt[d][k]
    #pragma unroll
    for (int dt = 0; dt < 4; dt++) {
      #pragma unroll
      for (int kc = 0; kc < 2; kc++) {
        s16x8 pf = *(const s16x8*)(PlB + lrow * 128 + ((64 * kc + 16 * lg) ^ ((lrow & 7) << 4)));
        int vrow = dt * 16 + lrow;
        s16x8 vf = *(const s16x8*)(VsB + vrow * 128 + ((64 * kc + 16 * lg) ^ ((vrow & 7) << 4)));
        o[dt] = MFMA16(pf, vf, o[dt]);
      }
    }
    __syncthreads();
  }
  #pragma unroll
  for (int r = 0; r < 4; r++) {
    float lr = bpermf(l_, lg * 4 + r);
    float inv = 1.0f / lr;
    int qrow = q0 + wid * 16 + lg * 4 + r;
    size_t orow = ((size_t)b * SEQ + qrow) * DM + h * 64;
    #pragma unroll
    for (int dt = 0; dt < 4; dt++)
      AO[orow + dt * 16 + lrow] = f2bf(o[dt][r] * inv);
  }
}

// ------------------------------------------------------------------------
extern "C" void kernel_launch(void* const* d_in, const int* in_sizes, int n_in,
                              void* d_out, int out_size, void* d_ws, size_t ws_size,
                              hipStream_t stream) {
  const float* kv  = (const float*)d_in[0];
  const float* q   = (const float*)d_in[1];
  const int*   msk = (const int*)d_in[2];
  const float* Wq  = (const float*)d_in[3];
  const float* bq  = (const float*)d_in[4];
  const float* Wk  = (const float*)d_in[5];
  const float* bk  = (const float*)d_in[6];
  const float* Wv  = (const float*)d_in[7];
  const float* bv  = (const float*)d_in[8];
  const float* qns = (const float*)d_in[9];
  const float* qnb = (const float*)d_in[10];
  const float* kns = (const float*)d_in[11];
  const float* knb = (const float*)d_in[12];
  const float* vns = (const float*)d_in[13];
  const float* vnb = (const float*)d_in[14];
  const float* Wo  = (const float*)d_in[15];
  const float* bo  = (const float*)d_in[16];
  float* out = (float*)d_out;
  char* ws = (char*)d_ws;
  const size_t MB = 1u << 20;

  short* wqt   = (short*)(ws + 0 * MB);
  short* wkt   = (short*)(ws + 2 * MB);
  short* wvt   = (short*)(ws + 4 * MB);
  short* wot   = (short*)(ws + 6 * MB);
  short* qb    = (short*)(ws + 8 * MB);
  short* kvb   = (short*)(ws + 24 * MB);
  float* Y     = (float*)(ws + 40 * MB);   // 32MB, dead after last LN
  short* Vt    = (short*)(ws + 40 * MB);   // aliases Y (16MB)
  short* AO    = (short*)(ws + 56 * MB);   // aliases Y (16MB)
  short* Qh    = (short*)(ws + 72 * MB);
  short* Kh    = (short*)(ws + 88 * MB);
  short* Vh    = (short*)(ws + 104 * MB);
  unsigned* mb = (unsigned*)(ws + 120 * MB);

  pack_mask<<<dim3(65536), dim3(256), 0, stream>>>(msk, mb);
  conv_bf16<<<dim3(ROWS * DM / 1024), dim3(256), 0, stream>>>(q, qb);
  conv_bf16<<<dim3(ROWS * DM / 1024), dim3(256), 0, stream>>>(kv, kvb);
  transpose_w<<<dim3(32, 32), dim3(32, 8), 0, stream>>>(Wq, wqt);
  transpose_w<<<dim3(32, 32), dim3(32, 8), 0, stream>>>(Wk, wkt);
  transpose_w<<<dim3(32, 32), dim3(32, 8), 0, stream>>>(Wv, wvt);
  transpose_w<<<dim3(32, 32), dim3(32, 8), 0, stream>>>(Wo, wot);

  gemm_bias<<<dim3(8, 64), dim3(256), 0, stream>>>(qb, wqt, bq, Y);
  ln_to_heads<<<dim3(ROWS), dim3(256), 0, stream>>>(Y, qns, qnb, Qh);
  gemm_bias<<<dim3(8, 64), dim3(256), 0, stream>>>(kvb, wkt, bk, Y);
  ln_to_heads<<<dim3(ROWS), dim3(256), 0, stream>>>(Y, kns, knb, Kh);
  gemm_bias<<<dim3(8, 64), dim3(256), 0, stream>>>(kvb, wvt, bv, Y);
  ln_to_heads<<<dim3(ROWS), dim3(256), 0, stream>>>(Y, vns, vnb, Vh);

  transpose_v<<<dim3(SEQ / 64, BS * NH), dim3(256), 0, stream>>>(Vh, Vt);

  attn<<<dim3(SEQ / 64, BS * NH), dim3(256), 0, stream>>>(Qh, Kh, Vt, mb, AO);

  gemm_bias<<<dim3(8, 64), dim3(256), 0, stream>>>(AO, wot, bo, out);
}

// Round 6
// 545.457 us; speedup vs baseline: 1.2181x; 1.0409x over previous
//
#include <hip/hip_runtime.h>
#include <hip/hip_bf16.h>

#define SEQ   2048
#define BS    4
#define DM    1024
#define NH    16
#define ROWS  (BS*SEQ)   // 8192

using s16x8 = __attribute__((ext_vector_type(8))) short;
using f32x4 = __attribute__((ext_vector_type(4))) float;

#define MFMA16(a,b,c) __builtin_amdgcn_mfma_f32_16x16x32_bf16(a,b,c,0,0,0)

__device__ __forceinline__ short f2bf(float f){
  union { float f; unsigned u; } v; v.f = f;
  unsigned r = (v.u + 0x7FFFu + ((v.u >> 16) & 1u)) >> 16;
  return (short)r;
}

__device__ __forceinline__ float bpermf(float v, int srcLane){
  union { float f; int i; } u; u.f = v;
  u.i = __builtin_amdgcn_ds_bpermute(srcLane * 4, u.i);
  return u.f;
}

// packed f32x2 -> bf16x2 (RNE), gfx950 hw instr  [T12 recipe, m240/m214v22]
__device__ __forceinline__ unsigned cvtpk_bf16(float lo, float hi){
  unsigned r;
  asm("v_cvt_pk_bf16_f32 %0, %1, %2" : "=v"(r) : "v"(lo), "v"(hi));
  return r;
}

__device__ __forceinline__ void gload_lds16(const void* g, void* l){
  __builtin_amdgcn_global_load_lds(
    (const __attribute__((address_space(1))) unsigned int*)g,
    (__attribute__((address_space(3))) unsigned int*)l, 16, 0, 0);
}

// ---------------- mask pack: int32 -> bit per element -------------------
__global__ __launch_bounds__(256) void pack_mask(const int* __restrict__ mask,
                                                 unsigned* __restrict__ bits){
  int t = blockIdx.x * 256 + threadIdx.x;
  unsigned long long b = __ballot(mask[t] != 0);
  int lane = threadIdx.x & 63;
  if (lane == 0)       bits[t >> 5] = (unsigned)b;
  else if (lane == 32) bits[t >> 5] = (unsigned)(b >> 32);
}

// ---------------- f32 -> bf16 convert ----------------------------------
__global__ __launch_bounds__(256) void conv_bf16(const float* __restrict__ in,
                                                 short* __restrict__ out){
  int t = blockIdx.x * 256 + threadIdx.x;
  float4 v = ((const float4*)in)[t];
  short4 o;
  o.x = f2bf(v.x); o.y = f2bf(v.y); o.z = f2bf(v.z); o.w = f2bf(v.w);
  ((short4*)out)[t] = o;
}

// ---------------- weight transpose+convert: W[k][n] -> Wt[n][k] bf16 ---
__global__ __launch_bounds__(256) void transpose_w(const float* __restrict__ W,
                                                   short* __restrict__ Wt){
  __shared__ float tile[32][33];
  int n0 = blockIdx.x * 32, k0 = blockIdx.y * 32;
  int tx = threadIdx.x, ty = threadIdx.y;   // (32,8)
  #pragma unroll
  for (int i = 0; i < 32; i += 8)
    tile[ty + i][tx] = W[(size_t)(k0 + ty + i) * DM + n0 + tx];
  __syncthreads();
  #pragma unroll
  for (int i = 0; i < 32; i += 8)
    Wt[(size_t)(n0 + ty + i) * DM + k0 + tx] = f2bf(tile[tx][ty + i]);
}

// ---------------- 128x128 bf16 GEMM (B^T input) + bias, f32 out --------
__global__ __launch_bounds__(256) void gemm_bias(const short* __restrict__ A,
                                                 const short* __restrict__ Bt,
                                                 const float* __restrict__ bias,
                                                 float* __restrict__ C){
  __shared__ short As[128 * 32];
  __shared__ short Bs[128 * 32];
  const int tid = threadIdx.x;
  const int wid = tid >> 6, lane = tid & 63;
  const int m0 = blockIdx.y * 128, n0 = blockIdx.x * 128;
  const int wr = (wid >> 1) * 64, wc = (wid & 1) * 64;
  const int lrow = lane & 15, lk = lane >> 4;
  f32x4 acc[4][4] = {};

  const int e0 = wid * 1024 + lane * 16;
  const int r0 = e0 >> 6, c0 = e0 & 63;
  const int e1 = e0 + 4096;
  const int r1 = e1 >> 6, c1 = e1 & 63;

  const char* Abase = (const char*)A + (size_t)m0 * 2048;
  const char* Bbase = (const char*)Bt + (size_t)n0 * 2048;
  char* AsB = (char*)As;
  char* BsB = (char*)Bs;

  for (int k0 = 0; k0 < DM; k0 += 32) {
    gload_lds16(Abase + (size_t)r0 * 2048 + k0 * 2 + c0, AsB + wid * 1024);
    gload_lds16(Abase + (size_t)r1 * 2048 + k0 * 2 + c1, AsB + 4096 + wid * 1024);
    gload_lds16(Bbase + (size_t)r0 * 2048 + k0 * 2 + c0, BsB + wid * 1024);
    gload_lds16(Bbase + (size_t)r1 * 2048 + k0 * 2 + c1, BsB + 4096 + wid * 1024);
    __syncthreads();
    s16x8 af[4], bf[4];
    #pragma unroll
    for (int mt = 0; mt < 4; mt++)
      af[mt] = *(const s16x8*)(AsB + ((wr + mt * 16 + lrow) * 64 + lk * 16));
    #pragma unroll
    for (int nt = 0; nt < 4; nt++)
      bf[nt] = *(const s16x8*)(BsB + ((wc + nt * 16 + lrow) * 64 + lk * 16));
    #pragma unroll
    for (int mt = 0; mt < 4; mt++)
      #pragma unroll
      for (int nt = 0; nt < 4; nt++)
        acc[mt][nt] = MFMA16(af[mt], bf[nt], acc[mt][nt]);
    __syncthreads();
  }
  #pragma unroll
  for (int nt = 0; nt < 4; nt++) {
    int col = n0 + wc + nt * 16 + lrow;
    float bv = bias[col];
    #pragma unroll
    for (int mt = 0; mt < 4; mt++) {
      #pragma unroll
      for (int r = 0; r < 4; r++) {
        int row = m0 + wr + mt * 16 + lk * 4 + r;
        C[(size_t)row * DM + col] = acc[mt][nt][r] + bv;
      }
    }
  }
}

// ---------------- LayerNorm + scale/bias (+out-scale) + head-split -----
__global__ __launch_bounds__(256) void ln_to_heads(const float* __restrict__ Y,
                                                   const float* __restrict__ sc,
                                                   const float* __restrict__ bi,
                                                   short* __restrict__ out,
                                                   float oscale){
  int row = blockIdx.x;                 // b*2048 + s
  int b = row >> 11, s = row & 2047;
  int tid = threadIdx.x;
  float4 v = ((const float4*)(Y + (size_t)row * DM))[tid];
  float sum = v.x + v.y + v.z + v.w;
  float sq  = v.x * v.x + v.y * v.y + v.z * v.z + v.w * v.w;
  #pragma unroll
  for (int o = 32; o; o >>= 1) { sum += __shfl_down(sum, o); sq += __shfl_down(sq, o); }
  __shared__ float red[8];
  int wid = tid >> 6, lane = tid & 63;
  if (!lane) { red[wid] = sum; red[wid + 4] = sq; }
  __syncthreads();
  sum = red[0] + red[1] + red[2] + red[3];
  sq  = red[4] + red[5] + red[6] + red[7];
  float mu = sum * (1.0f / DM);
  float var = sq * (1.0f / DM) - mu * mu;
  float rs = rsqrtf(var + 1e-6f);
  float4 scv = ((const float4*)sc)[tid];
  float4 biv = ((const float4*)bi)[tid];
  short4 o4;
  o4.x = f2bf(((v.x - mu) * rs * scv.x + biv.x) * oscale);
  o4.y = f2bf(((v.y - mu) * rs * scv.y + biv.y) * oscale);
  o4.z = f2bf(((v.z - mu) * rs * scv.z + biv.z) * oscale);
  o4.w = f2bf(((v.w - mu) * rs * scv.w + biv.w) * oscale);
  int c = tid * 4;
  int h = c >> 6, d = c & 63;
  *(short4*)(out + (((size_t)(b * NH + h) * SEQ + s) * 64 + d)) = o4;
}

// ---------------- V transpose: [bh][s][64] -> [bh][64][s] ---------------
__global__ __launch_bounds__(256) void transpose_v(const short* __restrict__ Vh,
                                                   short* __restrict__ Vt){
  __shared__ char t[8192];
  const int tid = threadIdx.x;
  const int bh = blockIdx.y;
  const int s0 = blockIdx.x * 64;
  const char* src = (const char*)(Vh + (size_t)bh * SEQ * 64 + (size_t)s0 * 64);
  char* dst = (char*)(Vt + (size_t)bh * 64 * SEQ + s0);
  #pragma unroll
  for (int p = 0; p < 2; p++) {
    int e = p * 4096 + tid * 16;
    int s = e >> 7, d2 = e & 127;
    s16x8 v = *(const s16x8*)(src + (size_t)s * 128 + d2);
    *(s16x8*)(t + s * 128 + (d2 ^ ((s & 7) << 4))) = v;
  }
  __syncthreads();
  #pragma unroll
  for (int p = 0; p < 2; p++) {
    int f = p * 4096 + tid * 16;
    int d = f >> 7;
    int sj = (f & 127) >> 1;
    s16x8 v;
    #pragma unroll
    for (int k = 0; k < 8; k++) {
      int s = sj + k;
      v[k] = *(const short*)(t + s * 128 + ((2 * d) ^ ((s & 7) << 4)));
    }
    *(s16x8*)(dst + (size_t)d * (SEQ * 2) + sj * 2) = v;
  }
}

// ---------------- flash attention (swapped QK^T, KVBLK=128) -------------
// Qh(pre-scaled 1/8)/Kh: [b][h][s][64] ; Vt: [b][h][64][s] ; AO: [b][s][DM]
__global__ __launch_bounds__(256) void attn(const short* __restrict__ Qh,
                                            const short* __restrict__ Kh,
                                            const short* __restrict__ VtG,
                                            const unsigned* __restrict__ mbits,
                                            short* __restrict__ AO){
  __shared__ short Ks[2][64 * 64];   // [k][d] rows swizzled ^((k&7)<<4)
  __shared__ short Vs[2][64 * 64];   // [d][s] rows swizzled ^((d&7)<<4)
  __shared__ short Pl[4][16 * 64];   // per-wave [q][k] rows swizzled ^((q&7)<<4)
  const int tid = threadIdx.x, wid = tid >> 6, lane = tid & 63;
  const int bh = blockIdx.y, b = bh >> 4, h = bh & 15;
  const int q0 = blockIdx.x * 64;
  const size_t bhoff = (size_t)bh * SEQ * 64;
  const int lrow = lane & 15, lg = lane >> 4;
  const float L2E = 1.44269504f;

  const int qidx = q0 + wid * 16 + lrow;      // this lane's softmax q-row
  s16x8 qf[2];
  {
    const short* qrow = Qh + bhoff + (size_t)qidx * 64 + lg * 8;
    qf[0] = *(const s16x8*)(qrow);
    qf[1] = *(const s16x8*)(qrow + 32);
  }
  f32x4 o[4] = {};
  float m_ = -1e9f, l_ = 0.f;

  const uint4* mrow = (const uint4*)(mbits + ((size_t)b * SEQ + qidx) * 64);

  // staging geometry (pre-swizzled global source, linear LDS dest)
  const int e0 = wid * 1024 + lane * 16;
  const int sr0 = e0 >> 7, sc0 = (e0 & 127) ^ ((sr0 & 7) << 4);
  const int e1 = e0 + 4096;
  const int sr1 = e1 >> 7, sc1 = (e1 & 127) ^ ((sr1 & 7) << 4);
  const char* Kbase = (const char*)(Kh + bhoff);
  const char* Vbase = (const char*)(VtG + bhoff);   // rows d, stride SEQ*2
  char* Ks0B = (char*)&Ks[0][0];
  char* Ks1B = (char*)&Ks[1][0];
  char* Vs0B = (char*)&Vs[0][0];
  char* Vs1B = (char*)&Vs[1][0];
  char* PlB = (char*)&Pl[wid][0];

  for (int k0 = 0; k0 < SEQ; k0 += 128) {
    gload_lds16(Kbase + (size_t)(k0 + sr0) * 128 + sc0,      Ks0B + wid * 1024);
    gload_lds16(Kbase + (size_t)(k0 + sr1) * 128 + sc1,      Ks0B + 4096 + wid * 1024);
    gload_lds16(Kbase + (size_t)(k0 + 64 + sr0) * 128 + sc0, Ks1B + wid * 1024);
    gload_lds16(Kbase + (size_t)(k0 + 64 + sr1) * 128 + sc1, Ks1B + 4096 + wid * 1024);
    gload_lds16(Vbase + (size_t)sr0 * (SEQ * 2) + k0 * 2 + sc0,       Vs0B + wid * 1024);
    gload_lds16(Vbase + (size_t)sr1 * (SEQ * 2) + k0 * 2 + sc1,       Vs0B + 4096 + wid * 1024);
    gload_lds16(Vbase + (size_t)sr0 * (SEQ * 2) + k0 * 2 + 128 + sc0, Vs1B + wid * 1024);
    gload_lds16(Vbase + (size_t)sr1 * (SEQ * 2) + k0 * 2 + 128 + sc1, Vs1B + 4096 + wid * 1024);
    uint4 mq = mrow[k0 >> 7];          // 128 mask bits for this tile
    __syncthreads();

    // swapped QK^T: lane owns q=qidx; chunk c: k = (c>>2)*64 + (c&3)*16 + lg*4 + r
    float sv[8][4];
    #pragma unroll
    for (int hf = 0; hf < 2; hf++) {
      const char* KB = hf ? Ks1B : Ks0B;
      #pragma unroll
      for (int kt = 0; kt < 4; kt++) {
        f32x4 sacc = {};
        #pragma unroll
        for (int cc = 0; cc < 2; cc++) {
          int krow = kt * 16 + lrow;
          s16x8 kf = *(const s16x8*)(KB + krow * 128 + ((lg * 16 + 64 * cc) ^ ((krow & 7) << 4)));
          sacc = MFMA16(kf, qf[cc], sacc);
        }
        unsigned w = hf ? (kt < 2 ? mq.z : mq.w) : (kt < 2 ? mq.x : mq.y);
        #pragma unroll
        for (int r = 0; r < 4; r++) {
          int bit = (kt & 1) * 16 + lg * 4 + r;
          sv[hf * 4 + kt][r] = ((w >> bit) & 1) ? sacc[r] : -1e9f;
        }
      }
    }
    // row max over 128 keys: in-lane tree + 2 shfls
    float tm = fmaxf(fmaxf(sv[0][0], sv[0][1]), fmaxf(sv[0][2], sv[0][3]));
    #pragma unroll
    for (int c = 1; c < 8; c++)
      tm = fmaxf(fmaxf(fmaxf(tm, sv[c][0]), fmaxf(sv[c][1], sv[c][2])), sv[c][3]);
    tm = fmaxf(tm, __shfl_xor(tm, 16));
    tm = fmaxf(tm, __shfl_xor(tm, 32));

    // defer-max rescale (THR=8)
    if (__any(tm > m_ + 8.0f)) {
      float mn = fmaxf(m_, tm);
      float scl = exp2f((m_ - mn) * L2E);
      m_ = mn;
      l_ *= scl;
      #pragma unroll
      for (int r = 0; r < 4; r++) {
        float scr = bpermf(scl, lg * 4 + r);
        o[0][r] *= scr; o[1][r] *= scr; o[2][r] *= scr; o[3][r] *= scr;
      }
    }

    float mL = m_ * L2E;
    float rsum = 0.f;
    #pragma unroll
    for (int hf = 0; hf < 2; hf++) {
      const char* VB = hf ? Vs1B : Vs0B;
      #pragma unroll
      for (int kt = 0; kt < 4; kt++) {
        int c = hf * 4 + kt;
        float ee0 = exp2f(sv[c][0] * L2E - mL);
        float ee1 = exp2f(sv[c][1] * L2E - mL);
        float ee2 = exp2f(sv[c][2] * L2E - mL);
        float ee3 = exp2f(sv[c][3] * L2E - mL);
        rsum += (ee0 + ee1) + (ee2 + ee3);
        uint2 wv = make_uint2(cvtpk_bf16(ee0, ee1), cvtpk_bf16(ee2, ee3));
        *(uint2*)(PlB + lrow * 128 + ((32 * kt + 8 * lg) ^ ((lrow & 7) << 4))) = wv;
      }
      // PV for this half: O[q][d] += P[q][k] * Vt[d][k]
      #pragma unroll
      for (int dt = 0; dt < 4; dt++) {
        #pragma unroll
        for (int kc = 0; kc < 2; kc++) {
          s16x8 pf = *(const s16x8*)(PlB + lrow * 128 + ((64 * kc + 16 * lg) ^ ((lrow & 7) << 4)));
          int vrow = dt * 16 + lrow;
          s16x8 vf = *(const s16x8*)(VB + vrow * 128 + ((64 * kc + 16 * lg) ^ ((vrow & 7) << 4)));
          o[dt] = MFMA16(pf, vf, o[dt]);
        }
      }
    }
    rsum += __shfl_xor(rsum, 16);
    rsum += __shfl_xor(rsum, 32);
    l_ += rsum;
    __syncthreads();
  }
  #pragma unroll
  for (int r = 0; r < 4; r++) {
    float lr = bpermf(l_, lg * 4 + r);
    float inv = 1.0f / lr;
    int qrow = q0 + wid * 16 + lg * 4 + r;
    size_t orow = ((size_t)b * SEQ + qrow) * DM + h * 64;
    #pragma unroll
    for (int dt = 0; dt < 4; dt++)
      AO[orow + dt * 16 + lrow] = f2bf(o[dt][r] * inv);
  }
}

// ------------------------------------------------------------------------
extern "C" void kernel_launch(void* const* d_in, const int* in_sizes, int n_in,
                              void* d_out, int out_size, void* d_ws, size_t ws_size,
                              hipStream_t stream) {
  const float* kv  = (const float*)d_in[0];
  const float* q   = (const float*)d_in[1];
  const int*   msk = (const int*)d_in[2];
  const float* Wq  = (const float*)d_in[3];
  const float* bq  = (const float*)d_in[4];
  const float* Wk  = (const float*)d_in[5];
  const float* bk  = (const float*)d_in[6];
  const float* Wv  = (const float*)d_in[7];
  const float* bv  = (const float*)d_in[8];
  const float* qns = (const float*)d_in[9];
  const float* qnb = (const float*)d_in[10];
  const float* kns = (const float*)d_in[11];
  const float* knb = (const float*)d_in[12];
  const float* vns = (const float*)d_in[13];
  const float* vnb = (const float*)d_in[14];
  const float* Wo  = (const float*)d_in[15];
  const float* bo  = (const float*)d_in[16];
  float* out = (float*)d_out;
  char* ws = (char*)d_ws;
  const size_t MB = 1u << 20;

  short* wqt   = (short*)(ws + 0 * MB);
  short* wkt   = (short*)(ws + 2 * MB);
  short* wvt   = (short*)(ws + 4 * MB);
  short* wot   = (short*)(ws + 6 * MB);
  short* qb    = (short*)(ws + 8 * MB);
  short* kvb   = (short*)(ws + 24 * MB);
  float* Y     = (float*)(ws + 40 * MB);   // 32MB, dead after last LN
  short* Vt    = (short*)(ws + 40 * MB);   // aliases Y (16MB)
  short* AO    = (short*)(ws + 56 * MB);   // aliases Y (16MB)
  short* Qh    = (short*)(ws + 72 * MB);
  short* Kh    = (short*)(ws + 88 * MB);
  short* Vh    = (short*)(ws + 104 * MB);
  unsigned* mb = (unsigned*)(ws + 120 * MB);

  pack_mask<<<dim3(65536), dim3(256), 0, stream>>>(msk, mb);
  conv_bf16<<<dim3(ROWS * DM / 1024), dim3(256), 0, stream>>>(q, qb);
  conv_bf16<<<dim3(ROWS * DM / 1024), dim3(256), 0, stream>>>(kv, kvb);
  transpose_w<<<dim3(32, 32), dim3(32, 8), 0, stream>>>(Wq, wqt);
  transpose_w<<<dim3(32, 32), dim3(32, 8), 0, stream>>>(Wk, wkt);
  transpose_w<<<dim3(32, 32), dim3(32, 8), 0, stream>>>(Wv, wvt);
  transpose_w<<<dim3(32, 32), dim3(32, 8), 0, stream>>>(Wo, wot);

  gemm_bias<<<dim3(8, 64), dim3(256), 0, stream>>>(qb, wqt, bq, Y);
  ln_to_heads<<<dim3(ROWS), dim3(256), 0, stream>>>(Y, qns, qnb, Qh, 0.125f);
  gemm_bias<<<dim3(8, 64), dim3(256), 0, stream>>>(kvb, wkt, bk, Y);
  ln_to_heads<<<dim3(ROWS), dim3(256), 0, stream>>>(Y, kns, knb, Kh, 1.0f);
  gemm_bias<<<dim3(8, 64), dim3(256), 0, stream>>>(kvb, wvt, bv, Y);
  ln_to_heads<<<dim3(ROWS), dim3(256), 0, stream>>>(Y, vns, vnb, Vh, 1.0f);

  transpose_v<<<dim3(SEQ / 64, BS * NH), dim3(256), 0, stream>>>(Vh, Vt);

  attn<<<dim3(SEQ / 64, BS * NH), dim3(256), 0, stream>>>(Qh, Kh, Vt, mb, AO);

  gemm_bias<<<dim3(8, 64), dim3(256), 0, stream>>>(AO, wot, bo, out);
}

// Round 12
// 492.904 us; speedup vs baseline: 1.3480x; 1.1066x over previous
//
#include <hip/hip_runtime.h>
#include <hip/hip_bf16.h>

#define SEQ   2048
#define BS    4
#define DM    1024
#define NH    16
#define ROWS  (BS*SEQ)   // 8192

using s16x8 = __attribute__((ext_vector_type(8))) short;
using f32x4 = __attribute__((ext_vector_type(4))) float;

#define MFMA16(a,b,c) __builtin_amdgcn_mfma_f32_16x16x32_bf16(a,b,c,0,0,0)

__device__ __forceinline__ short f2bf(float f){
  union { float f; unsigned u; } v; v.f = f;
  unsigned r = (v.u + 0x7FFFu + ((v.u >> 16) & 1u)) >> 16;
  return (short)r;
}

__device__ __forceinline__ float bf2f(short s){
  union { unsigned u; float f; } v; v.u = ((unsigned)(unsigned short)s) << 16;
  return v.f;
}

__device__ __forceinline__ float bpermf(float v, int srcLane){
  union { float f; int i; } u; u.f = v;
  u.i = __builtin_amdgcn_ds_bpermute(srcLane * 4, u.i);
  return u.f;
}

// packed f32x2 -> bf16x2 (RNE), gfx950 hw instr  [T12 recipe]
__device__ __forceinline__ unsigned cvtpk_bf16(float lo, float hi){
  unsigned r;
  asm("v_cvt_pk_bf16_f32 %0, %1, %2" : "=v"(r) : "v"(lo), "v"(hi));
  return r;
}

__device__ __forceinline__ void gload_lds16(const void* g, void* l){
  __builtin_amdgcn_global_load_lds(
    (const __attribute__((address_space(1))) unsigned int*)g,
    (__attribute__((address_space(3))) unsigned int*)l, 16, 0, 0);
}

// ---------------- mask pack: int32 -> bit per element -------------------
__global__ __launch_bounds__(256) void pack_mask(const int* __restrict__ mask,
                                                 unsigned* __restrict__ bits){
  int t = blockIdx.x * 256 + threadIdx.x;
  unsigned long long b = __ballot(mask[t] != 0);
  int lane = threadIdx.x & 63;
  if (lane == 0)       bits[t >> 5] = (unsigned)b;
  else if (lane == 32) bits[t >> 5] = (unsigned)(b >> 32);
}

// ---------------- f32 -> bf16 convert (q and kv in one launch) ---------
__global__ __launch_bounds__(256) void conv2_bf16(const float* __restrict__ q,
                                                  const float* __restrict__ kv,
                                                  short* __restrict__ qb,
                                                  short* __restrict__ kvb){
  int t = blockIdx.x * 256 + threadIdx.x;
  const float* in = blockIdx.y ? kv : q;
  short* out = blockIdx.y ? kvb : qb;
  float4 v = ((const float4*)in)[t];
  short4 o;
  o.x = f2bf(v.x); o.y = f2bf(v.y); o.z = f2bf(v.z); o.w = f2bf(v.w);
  ((short4*)out)[t] = o;
}

// ---------------- weight transpose+convert: 4 weights, one launch ------
__global__ __launch_bounds__(256) void transpose_w4(const float* __restrict__ Wq,
                                                    const float* __restrict__ Wk,
                                                    const float* __restrict__ Wv,
                                                    const float* __restrict__ Wo,
                                                    short* __restrict__ Wt4){
  __shared__ float tile[32][33];
  int z = blockIdx.z;
  const float* W = z == 0 ? Wq : (z == 1 ? Wk : (z == 2 ? Wv : Wo));
  short* Wt = Wt4 + (size_t)z * DM * DM;
  int n0 = blockIdx.x * 32, k0 = blockIdx.y * 32;
  int tx = threadIdx.x, ty = threadIdx.y;   // (32,8)
  #pragma unroll
  for (int i = 0; i < 32; i += 8)
    tile[ty + i][tx] = W[(size_t)(k0 + ty + i) * DM + n0 + tx];
  __syncthreads();
  #pragma unroll
  for (int i = 0; i < 32; i += 8)
    Wt[(size_t)(n0 + ty + i) * DM + k0 + tx] = f2bf(tile[tx][ty + i]);
}

// ---------------- fused Q/K/V projection GEMM, bf16 out ----------------
// z=0: qb*Wq^T+bq -> Yq ; z=1: kvb*Wk^T+bk -> Yk ; z=2: kvb*Wv^T+bv -> Yv
__global__ __launch_bounds__(256) void gemm_qkv(const short* __restrict__ qb,
                                                const short* __restrict__ kvb,
                                                const short* __restrict__ W4,
                                                const float* __restrict__ bq,
                                                const float* __restrict__ bk,
                                                const float* __restrict__ bv,
                                                short* __restrict__ Yq,
                                                short* __restrict__ Yk,
                                                short* __restrict__ Yv){
  __shared__ short As[128 * 32];
  __shared__ short Bs[128 * 32];
  const int z = blockIdx.z;
  const short* A = z ? kvb : qb;
  const short* Bt = W4 + (size_t)z * DM * DM;
  const float* bias = z == 0 ? bq : (z == 1 ? bk : bv);
  short* C = z == 0 ? Yq : (z == 1 ? Yk : Yv);

  const int tid = threadIdx.x;
  const int wid = tid >> 6, lane = tid & 63;
  const int m0 = blockIdx.y * 128, n0 = blockIdx.x * 128;
  const int wr = (wid >> 1) * 64, wc = (wid & 1) * 64;
  const int lrow = lane & 15, lk = lane >> 4;
  f32x4 acc[4][4] = {};

  const int e0 = wid * 1024 + lane * 16;
  const int r0 = e0 >> 6, c0 = e0 & 63;
  const int e1 = e0 + 4096;
  const int r1 = e1 >> 6, c1 = e1 & 63;

  const char* Abase = (const char*)A + (size_t)m0 * 2048;
  const char* Bbase = (const char*)Bt + (size_t)n0 * 2048;
  char* AsB = (char*)As;
  char* BsB = (char*)Bs;

  for (int k0 = 0; k0 < DM; k0 += 32) {
    gload_lds16(Abase + (size_t)r0 * 2048 + k0 * 2 + c0, AsB + wid * 1024);
    gload_lds16(Abase + (size_t)r1 * 2048 + k0 * 2 + c1, AsB + 4096 + wid * 1024);
    gload_lds16(Bbase + (size_t)r0 * 2048 + k0 * 2 + c0, BsB + wid * 1024);
    gload_lds16(Bbase + (size_t)r1 * 2048 + k0 * 2 + c1, BsB + 4096 + wid * 1024);
    __syncthreads();
    s16x8 af[4], bf[4];
    #pragma unroll
    for (int mt = 0; mt < 4; mt++)
      af[mt] = *(const s16x8*)(AsB + ((wr + mt * 16 + lrow) * 64 + lk * 16));
    #pragma unroll
    for (int nt = 0; nt < 4; nt++)
      bf[nt] = *(const s16x8*)(BsB + ((wc + nt * 16 + lrow) * 64 + lk * 16));
    #pragma unroll
    for (int mt = 0; mt < 4; mt++)
      #pragma unroll
      for (int nt = 0; nt < 4; nt++)
        acc[mt][nt] = MFMA16(af[mt], bf[nt], acc[mt][nt]);
    __syncthreads();
  }
  #pragma unroll
  for (int nt = 0; nt < 4; nt++) {
    int col = n0 + wc + nt * 16 + lrow;
    float bvv = bias[col];
    #pragma unroll
    for (int mt = 0; mt < 4; mt++) {
      #pragma unroll
      for (int r = 0; r < 4; r++) {
        int row = m0 + wr + mt * 16 + lk * 4 + r;
        C[(size_t)row * DM + col] = f2bf(acc[mt][nt][r] + bvv);
      }
    }
  }
}

// ---------------- 128x128 bf16 GEMM + bias, f32 out (final proj) -------
__global__ __launch_bounds__(256) void gemm_bias(const short* __restrict__ A,
                                                 const short* __restrict__ Bt,
                                                 const float* __restrict__ bias,
                                                 float* __restrict__ C){
  __shared__ short As[128 * 32];
  __shared__ short Bs[128 * 32];
  const int tid = threadIdx.x;
  const int wid = tid >> 6, lane = tid & 63;
  const int m0 = blockIdx.y * 128, n0 = blockIdx.x * 128;
  const int wr = (wid >> 1) * 64, wc = (wid & 1) * 64;
  const int lrow = lane & 15, lk = lane >> 4;
  f32x4 acc[4][4] = {};

  const int e0 = wid * 1024 + lane * 16;
  const int r0 = e0 >> 6, c0 = e0 & 63;
  const int e1 = e0 + 4096;
  const int r1 = e1 >> 6, c1 = e1 & 63;

  const char* Abase = (const char*)A + (size_t)m0 * 2048;
  const char* Bbase = (const char*)Bt + (size_t)n0 * 2048;
  char* AsB = (char*)As;
  char* BsB = (char*)Bs;

  for (int k0 = 0; k0 < DM; k0 += 32) {
    gload_lds16(Abase + (size_t)r0 * 2048 + k0 * 2 + c0, AsB + wid * 1024);
    gload_lds16(Abase + (size_t)r1 * 2048 + k0 * 2 + c1, AsB + 4096 + wid * 1024);
    gload_lds16(Bbase + (size_t)r0 * 2048 + k0 * 2 + c0, BsB + wid * 1024);
    gload_lds16(Bbase + (size_t)r1 * 2048 + k0 * 2 + c1, BsB + 4096 + wid * 1024);
    __syncthreads();
    s16x8 af[4], bf[4];
    #pragma unroll
    for (int mt = 0; mt < 4; mt++)
      af[mt] = *(const s16x8*)(AsB + ((wr + mt * 16 + lrow) * 64 + lk * 16));
    #pragma unroll
    for (int nt = 0; nt < 4; nt++)
      bf[nt] = *(const s16x8*)(BsB + ((wc + nt * 16 + lrow) * 64 + lk * 16));
    #pragma unroll
    for (int mt = 0; mt < 4; mt++)
      #pragma unroll
      for (int nt = 0; nt < 4; nt++)
        acc[mt][nt] = MFMA16(af[mt], bf[nt], acc[mt][nt]);
    __syncthreads();
  }
  #pragma unroll
  for (int nt = 0; nt < 4; nt++) {
    int col = n0 + wc + nt * 16 + lrow;
    float bv = bias[col];
    #pragma unroll
    for (int mt = 0; mt < 4; mt++) {
      #pragma unroll
      for (int r = 0; r < 4; r++) {
        int row = m0 + wr + mt * 16 + lk * 4 + r;
        C[(size_t)row * DM + col] = acc[mt][nt][r] + bv;
      }
    }
  }
}

// ---------------- LayerNorm (bf16 in) + scale/bias + head-split x3 -----
__global__ __launch_bounds__(256) void ln3_to_heads(const short* __restrict__ Yq,
                                                    const short* __restrict__ Yk,
                                                    const short* __restrict__ Yv,
                                                    const float* __restrict__ qs, const float* __restrict__ qb2,
                                                    const float* __restrict__ ks, const float* __restrict__ kb2,
                                                    const float* __restrict__ vs, const float* __restrict__ vb2,
                                                    short* __restrict__ Qh,
                                                    short* __restrict__ Kh,
                                                    short* __restrict__ Vh){
  const int z = blockIdx.y;
  const short* Y = z == 0 ? Yq : (z == 1 ? Yk : Yv);
  const float* sc = z == 0 ? qs : (z == 1 ? ks : vs);
  const float* bi = z == 0 ? qb2 : (z == 1 ? kb2 : vb2);
  short* out = z == 0 ? Qh : (z == 1 ? Kh : Vh);
  const float oscale = z == 0 ? 0.125f : 1.0f;

  int row = blockIdx.x;                 // b*2048 + s
  int b = row >> 11, s = row & 2047;
  int tid = threadIdx.x;
  short4 v4 = ((const short4*)(Y + (size_t)row * DM))[tid];
  float x0 = bf2f(v4.x), x1 = bf2f(v4.y), x2 = bf2f(v4.z), x3 = bf2f(v4.w);
  float sum = x0 + x1 + x2 + x3;
  float sq  = x0 * x0 + x1 * x1 + x2 * x2 + x3 * x3;
  #pragma unroll
  for (int o = 32; o; o >>= 1) { sum += __shfl_down(sum, o); sq += __shfl_down(sq, o); }
  __shared__ float red[8];
  int wid = tid >> 6, lane = tid & 63;
  if (!lane) { red[wid] = sum; red[wid + 4] = sq; }
  __syncthreads();
  sum = red[0] + red[1] + red[2] + red[3];
  sq  = red[4] + red[5] + red[6] + red[7];
  float mu = sum * (1.0f / DM);
  float var = sq * (1.0f / DM) - mu * mu;
  float rs = rsqrtf(var + 1e-6f);
  float4 scv = ((const float4*)sc)[tid];
  float4 biv = ((const float4*)bi)[tid];
  short4 o4;
  o4.x = f2bf(((x0 - mu) * rs * scv.x + biv.x) * oscale);
  o4.y = f2bf(((x1 - mu) * rs * scv.y + biv.y) * oscale);
  o4.z = f2bf(((x2 - mu) * rs * scv.z + biv.z) * oscale);
  o4.w = f2bf(((x3 - mu) * rs * scv.w + biv.w) * oscale);
  int c = tid * 4;
  int h = c >> 6, d = c & 63;
  *(short4*)(out + (((size_t)(b * NH + h) * SEQ + s) * 64 + d)) = o4;
}

// ---------------- V transpose: [bh][s][64] -> [bh][64][s] ---------------
__global__ __launch_bounds__(256) void transpose_v(const short* __restrict__ Vh,
                                                   short* __restrict__ Vt){
  __shared__ char t[8192];
  const int tid = threadIdx.x;
  const int bh = blockIdx.y;
  const int s0 = blockIdx.x * 64;
  const char* src = (const char*)(Vh + (size_t)bh * SEQ * 64 + (size_t)s0 * 64);
  char* dst = (char*)(Vt + (size_t)bh * 64 * SEQ + s0);
  #pragma unroll
  for (int p = 0; p < 2; p++) {
    int e = p * 4096 + tid * 16;
    int s = e >> 7, d2 = e & 127;
    s16x8 v = *(const s16x8*)(src + (size_t)s * 128 + d2);
    *(s16x8*)(t + s * 128 + (d2 ^ ((s & 7) << 4))) = v;
  }
  __syncthreads();
  #pragma unroll
  for (int p = 0; p < 2; p++) {
    int f = p * 4096 + tid * 16;
    int d = f >> 7;
    int sj = (f & 127) >> 1;
    s16x8 v;
    #pragma unroll
    for (int k = 0; k < 8; k++) {
      int s = sj + k;
      v[k] = *(const short*)(t + s * 128 + ((2 * d) ^ ((s & 7) << 4)));
    }
    *(s16x8*)(dst + (size_t)d * (SEQ * 2) + sj * 2) = v;
  }
}

// ---------------- flash attention (swapped QK^T, fixed-max softmax) ----
// Qh(pre-scaled 1/8)/Kh: [b][h][s][64] ; Vt: [b][h][64][s] ; AO: [b][s][DM]
// softmax shift-invariance: e = exp2(s*L2E - 16) = e^s * 2^-16; constant
// factor cancels in normalization. masked s=-1e9 -> exp2(-1.4e9) = 0.
__global__ __launch_bounds__(256) void attn(const short* __restrict__ Qh,
                                            const short* __restrict__ Kh,
                                            const short* __restrict__ VtG,
                                            const unsigned* __restrict__ mbits,
                                            short* __restrict__ AO){
  __shared__ short Ks[2][64 * 64];   // [k][d] rows swizzled ^((k&7)<<4)
  __shared__ short Vs[2][64 * 64];   // [d][s] rows swizzled ^((d&7)<<4)
  __shared__ short Pl[4][16 * 64];   // per-wave [q][k] rows swizzled ^((q&7)<<4)
  const int tid = threadIdx.x, wid = tid >> 6, lane = tid & 63;
  const int bh = blockIdx.y, b = bh >> 4, h = bh & 15;
  const int q0 = blockIdx.x * 64;
  const size_t bhoff = (size_t)bh * SEQ * 64;
  const int lrow = lane & 15, lg = lane >> 4;
  const float L2E = 1.44269504f;

  const int qidx = q0 + wid * 16 + lrow;      // this lane's softmax q-row
  s16x8 qf[2];
  {
    const short* qrow = Qh + bhoff + (size_t)qidx * 64 + lg * 8;
    qf[0] = *(const s16x8*)(qrow);
    qf[1] = *(const s16x8*)(qrow + 32);
  }
  f32x4 o[4] = {};
  float l_ = 0.f;

  const uint4* mrow = (const uint4*)(mbits + ((size_t)b * SEQ + qidx) * 64);

  // staging geometry (pre-swizzled global source, linear LDS dest)
  const int e0 = wid * 1024 + lane * 16;
  const int sr0 = e0 >> 7, sc0 = (e0 & 127) ^ ((sr0 & 7) << 4);
  const int e1 = e0 + 4096;
  const int sr1 = e1 >> 7, sc1 = (e1 & 127) ^ ((sr1 & 7) << 4);
  const char* Kbase = (const char*)(Kh + bhoff);
  const char* Vbase = (const char*)(VtG + bhoff);   // rows d, stride SEQ*2
  char* Ks0B = (char*)&Ks[0][0];
  char* Ks1B = (char*)&Ks[1][0];
  char* Vs0B = (char*)&Vs[0][0];
  char* Vs1B = (char*)&Vs[1][0];
  char* PlB = (char*)&Pl[wid][0];

  for (int k0 = 0; k0 < SEQ; k0 += 128) {
    gload_lds16(Kbase + (size_t)(k0 + sr0) * 128 + sc0,      Ks0B + wid * 1024);
    gload_lds16(Kbase + (size_t)(k0 + sr1) * 128 + sc1,      Ks0B + 4096 + wid * 1024);
    gload_lds16(Kbase + (size_t)(k0 + 64 + sr0) * 128 + sc0, Ks1B + wid * 1024);
    gload_lds16(Kbase + (size_t)(k0 + 64 + sr1) * 128 + sc1, Ks1B + 4096 + wid * 1024);
    gload_lds16(Vbase + (size_t)sr0 * (SEQ * 2) + k0 * 2 + sc0,       Vs0B + wid * 1024);
    gload_lds16(Vbase + (size_t)sr1 * (SEQ * 2) + k0 * 2 + sc1,       Vs0B + 4096 + wid * 1024);
    gload_lds16(Vbase + (size_t)sr0 * (SEQ * 2) + k0 * 2 + 128 + sc0, Vs1B + wid * 1024);
    gload_lds16(Vbase + (size_t)sr1 * (SEQ * 2) + k0 * 2 + 128 + sc1, Vs1B + 4096 + wid * 1024);
    uint4 mq = mrow[k0 >> 7];          // 128 mask bits for this tile
    __syncthreads();

    float rsum = 0.f;
    #pragma unroll
    for (int hf = 0; hf < 2; hf++) {
      const char* KB = hf ? Ks1B : Ks0B;
      const char* VB = hf ? Vs1B : Vs0B;
      // QK^T + fixed-max exp + P pack for 4 chunks of 16 keys
      #pragma unroll
      for (int kt = 0; kt < 4; kt++) {
        f32x4 sacc = {};
        #pragma unroll
        for (int cc = 0; cc < 2; cc++) {
          int krow = kt * 16 + lrow;
          s16x8 kf = *(const s16x8*)(KB + krow * 128 + ((lg * 16 + 64 * cc) ^ ((krow & 7) << 4)));
          sacc = MFMA16(kf, qf[cc], sacc);
        }
        unsigned w = hf ? (kt < 2 ? mq.z : mq.w) : (kt < 2 ? mq.x : mq.y);
        float e[4];
        #pragma unroll
        for (int r = 0; r < 4; r++) {
          int bit = (kt & 1) * 16 + lg * 4 + r;
          float s = ((w >> bit) & 1) ? sacc[r] : -1e9f;
          e[r] = exp2f(fmaf(s, L2E, -16.0f));
        }
        rsum += (e[0] + e[1]) + (e[2] + e[3]);
        uint2 wv = make_uint2(cvtpk_bf16(e[0], e[1]), cvtpk_bf16(e[2], e[3]));
        *(uint2*)(PlB + lrow * 128 + ((32 * kt + 8 * lg) ^ ((lrow & 7) << 4))) = wv;
      }
      // PV for this half: O[q][d] += P[q][k] * Vt[d][k]
      #pragma unroll
      for (int dt = 0; dt < 4; dt++) {
        #pragma unroll
        for (int kc = 0; kc < 2; kc++) {
          s16x8 pf = *(const s16x8*)(PlB + lrow * 128 + ((64 * kc + 16 * lg) ^ ((lrow & 7) << 4)));
          int vrow = dt * 16 + lrow;
          s16x8 vf = *(const s16x8*)(VB + vrow * 128 + ((64 * kc + 16 * lg) ^ ((vrow & 7) << 4)));
          o[dt] = MFMA16(pf, vf, o[dt]);
        }
      }
    }
    l_ += rsum;
    __syncthreads();
  }
  l_ += __shfl_xor(l_, 16);
  l_ += __shfl_xor(l_, 32);
  #pragma unroll
  for (int r = 0; r < 4; r++) {
    float lr = bpermf(l_, lg * 4 + r);
    float inv = 1.0f / lr;
    int qrow = q0 + wid * 16 + lg * 4 + r;
    size_t orow = ((size_t)b * SEQ + qrow) * DM + h * 64;
    #pragma unroll
    for (int dt = 0; dt < 4; dt++)
      AO[orow + dt * 16 + lrow] = f2bf(o[dt][r] * inv);
  }
}

// ------------------------------------------------------------------------
extern "C" void kernel_launch(void* const* d_in, const int* in_sizes, int n_in,
                              void* d_out, int out_size, void* d_ws, size_t ws_size,
                              hipStream_t stream) {
  const float* kv  = (const float*)d_in[0];
  const float* q   = (const float*)d_in[1];
  const int*   msk = (const int*)d_in[2];
  const float* Wq  = (const float*)d_in[3];
  const float* bq  = (const float*)d_in[4];
  const float* Wk  = (const float*)d_in[5];
  const float* bk  = (const float*)d_in[6];
  const float* Wv  = (const float*)d_in[7];
  const float* bv  = (const float*)d_in[8];
  const float* qns = (const float*)d_in[9];
  const float* qnb = (const float*)d_in[10];
  const float* kns = (const float*)d_in[11];
  const float* knb = (const float*)d_in[12];
  const float* vns = (const float*)d_in[13];
  const float* vnb = (const float*)d_in[14];
  const float* Wo  = (const float*)d_in[15];
  const float* bo  = (const float*)d_in[16];
  float* out = (float*)d_out;
  char* ws = (char*)d_ws;
  const size_t MB = 1u << 20;

  short* W4    = (short*)(ws + 0 * MB);    // wq,wk,wv,wo @ 0,2,4,6 MB
  short* qb    = (short*)(ws + 8 * MB);    // 16MB (bf16 8192x1024)
  short* kvb   = (short*)(ws + 24 * MB);   // 16MB
  short* Yq    = (short*)(ws + 40 * MB);   // 16MB bf16
  short* Yk    = (short*)(ws + 56 * MB);   // 16MB
  short* Yv    = (short*)(ws + 72 * MB);   // 16MB
  short* Qh    = (short*)(ws + 88 * MB);
  short* Kh    = (short*)(ws + 104 * MB);
  short* Vh    = (short*)(ws + 120 * MB);
  short* Vt    = (short*)(ws + 8 * MB);    // aliases qb (dead after gemm_qkv)
  short* AO    = (short*)(ws + 40 * MB);   // aliases Yq (dead after ln3)
  unsigned* mb = (unsigned*)(ws + 136 * MB);
  short* wot   = W4 + (size_t)3 * DM * DM;

  pack_mask<<<dim3(65536), dim3(256), 0, stream>>>(msk, mb);
  conv2_bf16<<<dim3(ROWS * DM / 1024, 2), dim3(256), 0, stream>>>(q, kv, qb, kvb);
  transpose_w4<<<dim3(32, 32, 4), dim3(32, 8), 0, stream>>>(Wq, Wk, Wv, Wo, W4);

  gemm_qkv<<<dim3(8, 64, 3), dim3(256), 0, stream>>>(qb, kvb, W4, bq, bk, bv, Yq, Yk, Yv);
  ln3_to_heads<<<dim3(ROWS, 3), dim3(256), 0, stream>>>(Yq, Yk, Yv, qns, qnb, kns, knb,
                                                        vns, vnb, Qh, Kh, Vh);

  transpose_v<<<dim3(SEQ / 64, BS * NH), dim3(256), 0, stream>>>(Vh, Vt);

  attn<<<dim3(SEQ / 64, BS * NH), dim3(256), 0, stream>>>(Qh, Kh, Vt, mb, AO);

  gemm_bias<<<dim3(8, 64), dim3(256), 0, stream>>>(AO, wot, bo, out);
}